// Round 1
// baseline (568.948 us; speedup 1.0000x reference)
//
#include <hip/hip_runtime.h>
#include <hip/hip_bf16.h>
#include <math.h>

#define B_ 2
#define S_ 2048
#define D_ 1024
#define H_ 4
#define DK_ 256
#define NJ 24
#define NG 96
#define QT 32
#define KT 32

// ---------------- kernel 1: fold Wq into proj ----------------
// M[d][hj] = sum_k Wq_w[h*256+k][d] * proj_w[j][k]
__global__ __launch_bounds__(256) void k_fuse(const float* __restrict__ Wq_w,
                                              const float* __restrict__ proj_w,
                                              float* __restrict__ M) {
  int tid = blockIdx.x * 256 + threadIdx.x;  // 96*1024 threads
  int hj = tid >> 10;
  int d = tid & 1023;
  int h = hj / NJ, j = hj - h * NJ;
  const float* wq = Wq_w + (size_t)(h * DK_) * D_ + d;
  const float* pw = proj_w + j * DK_;
  float acc = 0.f;
#pragma unroll 8
  for (int k = 0; k < DK_; ++k) acc += wq[(size_t)k * D_] * pw[k];
  M[(size_t)d * NG + hj] = acc;
}

// cbias[hj] = sum_k Wq_b[h*256+k]*proj_w[j][k] + proj_b[j]
__global__ void k_fuse_bias(const float* __restrict__ Wq_b,
                            const float* __restrict__ proj_w,
                            const float* __restrict__ proj_b,
                            float* __restrict__ cbias) {
  int hj = threadIdx.x;
  if (hj < NG) {
    int h = hj / NJ, j = hj - h * NJ;
    float acc = proj_b[j];
    for (int k = 0; k < DK_; ++k) acc += Wq_b[h * DK_ + k] * proj_w[j * DK_ + k];
    cbias[hj] = acc;
  }
}

// ---------------- psi from gen rows (8 rows per block) ----------------
__device__ __forceinline__ void psi_store(const float (*genL)[NG], int t, int g0,
                                          float* __restrict__ po,
                                          float* __restrict__ n2o) {
  if (t < 64) {
    int h = t >> 4, ii = t & 15, j = ii & 7;
#pragma unroll 2
    for (int r = 0; r < 8; ++r) {
      int g = g0 + r;
      int b = g >> 11, s = g & (S_ - 1);
      const float* gl = genL[r] + h * NJ;
      float A = gl[j], Bg = gl[8 + j];
      float Th = fminf(fmaxf(gl[16 + j], -8.f), 8.f);
      float val = (ii < 8) ? (A * expf(Th) + Bg * cosf(Th)) : (Bg * sinf(Th));
      size_t base = (size_t)(b * H_ + h) * S_ + s;
      po[base * 16 + ii] = val;
      float sq = val * val;
#pragma unroll
      for (int off = 1; off < 16; off <<= 1) sq += __shfl_xor(sq, off);
      if (ii == 0) n2o[base] = sq;
    }
  }
}

// ---------------- gen_q = Q_input @ M + cbias, then psi ----------------
__global__ __launch_bounds__(128) void k_genq(const float* __restrict__ Q,
                                              const float* __restrict__ M,
                                              const float* __restrict__ cbias,
                                              float* __restrict__ pq,
                                              float* __restrict__ qn2) {
  __shared__ float qlds[8][D_];
  __shared__ float genL[8][NG];
  int t = threadIdx.x;
  int g0 = blockIdx.x * 8;
  {
    const float4* src = (const float4*)(Q + (size_t)g0 * D_);
    float4* dst = (float4*)&qlds[0][0];
#pragma unroll
    for (int u = 0; u < 16; ++u) dst[t + 128 * u] = src[t + 128 * u];
  }
  __syncthreads();
  if (t < NG) {
    float cb = cbias[t];
    float acc[8];
#pragma unroll
    for (int r = 0; r < 8; ++r) acc[r] = cb;
    const float* Mp = M + t;
#pragma unroll 2
    for (int d0 = 0; d0 < D_; d0 += 4) {
      float m0 = Mp[(size_t)(d0 + 0) * NG];
      float m1 = Mp[(size_t)(d0 + 1) * NG];
      float m2 = Mp[(size_t)(d0 + 2) * NG];
      float m3 = Mp[(size_t)(d0 + 3) * NG];
#pragma unroll
      for (int r = 0; r < 8; ++r) {
        float4 q4 = *(const float4*)&qlds[r][d0];
        acc[r] += q4.x * m0 + q4.y * m1 + q4.z * m2 + q4.w * m3;
      }
    }
#pragma unroll
    for (int r = 0; r < 8; ++r) genL[r][t] = acc[r];
  }
  __syncthreads();
  psi_store(genL, t, g0, pq, qn2);
}

// ---------------- gen_k = K_head @ proj_w.T + proj_b, then psi ----------------
__global__ __launch_bounds__(128) void k_genk(const float* __restrict__ Kin,
                                              const float* __restrict__ proj_w,
                                              const float* __restrict__ proj_b,
                                              float* __restrict__ pk,
                                              float* __restrict__ kn2) {
  __shared__ float klds[8][D_];
  __shared__ float genL[8][NG];
  __shared__ float pwT[DK_][NJ];
  int t = threadIdx.x;
  int g0 = blockIdx.x * 8;
  {
    const float4* src = (const float4*)(Kin + (size_t)g0 * D_);
    float4* dst = (float4*)&klds[0][0];
#pragma unroll
    for (int u = 0; u < 16; ++u) dst[t + 128 * u] = src[t + 128 * u];
  }
  for (int idx = t; idx < NJ * DK_; idx += 128) {
    int j = idx >> 8, c = idx & 255;
    pwT[c][j] = proj_w[idx];
  }
  __syncthreads();
  if (t < NG) {
    int h = t / NJ, j = t - h * NJ;
    float pb = proj_b[j];
    float acc[8];
#pragma unroll
    for (int r = 0; r < 8; ++r) acc[r] = pb;
#pragma unroll 2
    for (int c0 = 0; c0 < DK_; c0 += 4) {
      float w0 = pwT[c0][j], w1 = pwT[c0 + 1][j];
      float w2 = pwT[c0 + 2][j], w3 = pwT[c0 + 3][j];
#pragma unroll
      for (int r = 0; r < 8; ++r) {
        float4 k4 = *(const float4*)&klds[r][h * DK_ + c0];
        acc[r] += k4.x * w0 + k4.y * w1 + k4.z * w2 + k4.w * w3;
      }
    }
#pragma unroll
    for (int r = 0; r < 8; ++r) genL[r][t] = acc[r];
  }
  __syncthreads();
  psi_store(genL, t, g0, pk, kn2);
}

// ---------------- flash-style geometric attention ----------------
__global__ __launch_bounds__(256) void k_attn(
    const float* __restrict__ pq, const float* __restrict__ qn2,
    const float* __restrict__ pk, const float* __restrict__ kn2,
    const float* __restrict__ V, const float* __restrict__ geo_w,
    const float* __restrict__ temp, float* __restrict__ attn_out) {
  __shared__ float pqs[QT][17];
  __shared__ float pkT[16][36];
  __shared__ float Pt[KT][36];
  __shared__ float Vs[KT][260];
  __shared__ float kn2s[KT], khs[KT];
  __shared__ float mL[QT], lL[QT], fL[QT];
  __shared__ float qn2s[QT], qhs[QT];

  int t = threadIdx.x;
  int bid = blockIdx.x;
  int qt = bid & 63;
  int bh = bid >> 6;          // b*H + h
  int h = bh & (H_ - 1);
  int b = bh >> 2;
  int q0 = qt * QT;
  const float* pqb = pq + ((size_t)bh * S_ + q0) * 16;
  const float* pkb = pk + (size_t)bh * S_ * 16;
  const float* Vb = V + (size_t)b * S_ * D_ + h * DK_;

  float g0w = geo_w[0], g1w = geo_w[1], g2w = geo_w[2], g3w = geo_w[3];
  float scale = 1.f / (4.f * temp[0]);

  if (t < QT) {
    mL[t] = -INFINITY;
    lL[t] = 0.f;
    float qv = qn2[(size_t)bh * S_ + q0 + t];
    qn2s[t] = qv;
    qhs[t] = sqrtf(qv + 1e-6f);
  }
  if (t < 128) {
    int r = t >> 2, i0 = (t & 3) * 4;
    float4 v = *(const float4*)(pqb + r * 16 + i0);
    pqs[r][i0] = v.x; pqs[r][i0 + 1] = v.y;
    pqs[r][i0 + 2] = v.z; pqs[r][i0 + 3] = v.w;
  }
  __syncthreads();

  int sr = t >> 3, scn = t & 7;   // score mapping: row sr, k-quad scn
  float qreg[16];
#pragma unroll
  for (int i = 0; i < 16; ++i) qreg[i] = pqs[sr][i];
  float myqn2 = qn2s[sr], myqh = qhs[sr];

  int rg = t >> 5, cg = t & 31;   // PV mapping: rows rg*4.., f4 cols cg, cg+32
  float acc[4][8];
#pragma unroll
  for (int rr = 0; rr < 4; ++rr)
#pragma unroll
    for (int u = 0; u < 8; ++u) acc[rr][u] = 0.f;

  for (int kt = 0; kt < S_ / KT; ++kt) {
    int k0 = kt * KT;
    if (t < 128) {  // stage pk transposed
      int k = t >> 2, i0 = (t & 3) * 4;
      float4 v = *(const float4*)(pkb + (size_t)(k0 + k) * 16 + i0);
      pkT[i0][k] = v.x; pkT[i0 + 1][k] = v.y;
      pkT[i0 + 2][k] = v.z; pkT[i0 + 3][k] = v.w;
    } else if (t < 128 + KT) {
      int k = t - 128;
      float kv = kn2[(size_t)bh * S_ + k0 + k];
      kn2s[k] = kv;
      khs[k] = sqrtf(kv + 1e-6f);
    }
    {  // stage V tile
      int k = t >> 3, c = t & 7;
      const float* vsrc = Vb + (size_t)(k0 + k) * D_;
      float4* vdst = (float4*)Vs[k];
#pragma unroll
      for (int u = 0; u < 8; ++u)
        vdst[c + 8 * u] = *(const float4*)(vsrc + (c + 8 * u) * 4);
    }
    __syncthreads();

    // scores: thread (sr, scn) computes k = scn*4..scn*4+3
    float tns[4] = {0.f, 0.f, 0.f, 0.f}, spn[4] = {0.f, 0.f, 0.f, 0.f};
#pragma unroll
    for (int i = 0; i < 8; ++i) {
      float4 ka = *(const float4*)&pkT[i][scn * 4];
      float4 kb = *(const float4*)&pkT[i + 8][scn * 4];
      float qa = qreg[i], qb = qreg[i + 8];
      tns[0] += qa * ka.x + qb * kb.x;
      tns[1] += qa * ka.y + qb * kb.y;
      tns[2] += qa * ka.z + qb * kb.z;
      tns[3] += qa * ka.w + qb * kb.w;
      spn[0] += qa * kb.x - qb * ka.x;
      spn[1] += qa * kb.y - qb * ka.y;
      spn[2] += qa * kb.z - qb * ka.z;
      spn[3] += qa * kb.w - qb * ka.w;
    }
    float sc4[4];
    float tmax = -INFINITY;
#pragma unroll
    for (int kk = 0; kk < 4; ++kk) {
      int k = scn * 4 + kk;
      float tn = tns[kk], sp = spn[kk];
      float gram = myqn2 * kn2s[k];
      float wedge = sqrtf(fmaxf(gram - tn * tn - sp * sp, 0.f) + 1e-6f);
      float sv = (g0w * wedge + g1w * tn + g2w * sp + g3w * (myqh * khs[k])) * scale;
      sc4[kk] = sv;
      tmax = fmaxf(tmax, sv);
    }
#pragma unroll
    for (int off = 1; off < 8; off <<= 1) tmax = fmaxf(tmax, __shfl_xor(tmax, off));
    float mo = mL[sr];
    float mn = fmaxf(mo, tmax);
    float pv4[4], psum = 0.f;
#pragma unroll
    for (int kk = 0; kk < 4; ++kk) {
      pv4[kk] = __expf(sc4[kk] - mn);
      psum += pv4[kk];
    }
#pragma unroll
    for (int off = 1; off < 8; off <<= 1) psum += __shfl_xor(psum, off);
    float fsc = __expf(mo - mn);
    if (scn == 0) { mL[sr] = mn; lL[sr] = lL[sr] * fsc + psum; fL[sr] = fsc; }
#pragma unroll
    for (int kk = 0; kk < 4; ++kk) Pt[scn * 4 + kk][sr] = pv4[kk];
    __syncthreads();

    // PV: rows rg*4+rr, dk = cg*4+i and 128+cg*4+i
    float fr[4];
#pragma unroll
    for (int rr = 0; rr < 4; ++rr) fr[rr] = fL[rg * 4 + rr];
#pragma unroll
    for (int rr = 0; rr < 4; ++rr)
#pragma unroll
      for (int u = 0; u < 8; ++u) acc[rr][u] *= fr[rr];
#pragma unroll 4
    for (int kk = 0; kk < KT; ++kk) {
      float4 pt4 = *(const float4*)&Pt[kk][rg * 4];
      float4 va = ((const float4*)Vs[kk])[cg];
      float4 vb = ((const float4*)Vs[kk])[cg + 32];
      float pr[4] = {pt4.x, pt4.y, pt4.z, pt4.w};
#pragma unroll
      for (int rr = 0; rr < 4; ++rr) {
        acc[rr][0] += pr[rr] * va.x;
        acc[rr][1] += pr[rr] * va.y;
        acc[rr][2] += pr[rr] * va.z;
        acc[rr][3] += pr[rr] * va.w;
        acc[rr][4] += pr[rr] * vb.x;
        acc[rr][5] += pr[rr] * vb.y;
        acc[rr][6] += pr[rr] * vb.z;
        acc[rr][7] += pr[rr] * vb.w;
      }
    }
    __syncthreads();
  }

#pragma unroll
  for (int rr = 0; rr < 4; ++rr) {
    int r = rg * 4 + rr;
    float linv = 1.f / lL[r];
    float* dst = attn_out + ((size_t)b * S_ + q0 + r) * D_ + h * DK_;
    float4 o0 = make_float4(acc[rr][0] * linv, acc[rr][1] * linv,
                            acc[rr][2] * linv, acc[rr][3] * linv);
    float4 o1 = make_float4(acc[rr][4] * linv, acc[rr][5] * linv,
                            acc[rr][6] * linv, acc[rr][7] * linv);
    *(float4*)(dst + cg * 4) = o0;
    *(float4*)(dst + 128 + cg * 4) = o1;
  }
}

// ---------------- output projection: C = A @ W^T + bias ----------------
__global__ __launch_bounds__(256) void k_wo(const float* __restrict__ A,
                                            const float* __restrict__ W,
                                            const float* __restrict__ bias,
                                            float* __restrict__ C) {
  __shared__ float As[32][68];
  __shared__ float Bs[32][68];
  int t = threadIdx.x;
  int tx = t & 15, ty = t >> 4;
  int n0 = blockIdx.x * 64;
  int m0 = blockIdx.y * 64;
  float acc[4][4];
#pragma unroll
  for (int i = 0; i < 4; ++i)
#pragma unroll
    for (int j = 0; j < 4; ++j) acc[i][j] = 0.f;

  for (int k0 = 0; k0 < D_; k0 += 32) {
#pragma unroll
    for (int u = 0; u < 2; ++u) {
      int idx = t + 256 * u;
      int row = idx >> 3, cf = idx & 7;
      float4 a = *(const float4*)(A + (size_t)(m0 + row) * D_ + k0 + cf * 4);
      As[cf * 4 + 0][row] = a.x; As[cf * 4 + 1][row] = a.y;
      As[cf * 4 + 2][row] = a.z; As[cf * 4 + 3][row] = a.w;
      float4 bb = *(const float4*)(W + (size_t)(n0 + row) * D_ + k0 + cf * 4);
      Bs[cf * 4 + 0][row] = bb.x; Bs[cf * 4 + 1][row] = bb.y;
      Bs[cf * 4 + 2][row] = bb.z; Bs[cf * 4 + 3][row] = bb.w;
    }
    __syncthreads();
#pragma unroll 8
    for (int kk = 0; kk < 32; ++kk) {
      float4 a4 = *(const float4*)&As[kk][ty * 4];
      float4 b4 = *(const float4*)&Bs[kk][tx * 4];
      float av[4] = {a4.x, a4.y, a4.z, a4.w};
      float bv[4] = {b4.x, b4.y, b4.z, b4.w};
#pragma unroll
      for (int i = 0; i < 4; ++i)
#pragma unroll
        for (int j = 0; j < 4; ++j) acc[i][j] += av[i] * bv[j];
    }
    __syncthreads();
  }
  float4 b4 = *(const float4*)(bias + n0 + tx * 4);
  float bv[4] = {b4.x, b4.y, b4.z, b4.w};
#pragma unroll
  for (int i = 0; i < 4; ++i) {
    float4 o = make_float4(acc[i][0] + bv[0], acc[i][1] + bv[1],
                           acc[i][2] + bv[2], acc[i][3] + bv[3]);
    *(float4*)(C + (size_t)(m0 + ty * 4 + i) * D_ + n0 + tx * 4) = o;
  }
}

extern "C" void kernel_launch(void* const* d_in, const int* in_sizes, int n_in,
                              void* d_out, int out_size, void* d_ws, size_t ws_size,
                              hipStream_t stream) {
  const float* Q_input = (const float*)d_in[0];
  const float* K = (const float*)d_in[1];
  const float* V = (const float*)d_in[2];
  // d_in[3] = T_field: unused by the reference
  const float* Wq_w = (const float*)d_in[4];
  const float* Wq_b = (const float*)d_in[5];
  const float* Wo_w = (const float*)d_in[6];
  const float* Wo_b = (const float*)d_in[7];
  const float* proj_w = (const float*)d_in[8];
  const float* proj_b = (const float*)d_in[9];
  const float* geo_w = (const float*)d_in[10];
  const float* temp = (const float*)d_in[11];

  float* ws = (float*)d_ws;
  float* M = ws;                       // 1024*96      = 98304
  float* cbias = M + 98304;            // 96 (pad 128)
  float* pq = cbias + 128;             // 2*4*2048*16  = 262144
  float* qn2 = pq + 262144;            // 16384
  float* pk = qn2 + 16384;             // 262144
  float* kn2 = pk + 262144;            // 16384
  float* attn = kn2 + 16384;           // 2*2048*1024  = 4194304
  float* out = (float*)d_out;

  k_fuse<<<dim3(384), dim3(256), 0, stream>>>(Wq_w, proj_w, M);
  k_fuse_bias<<<dim3(1), dim3(128), 0, stream>>>(Wq_b, proj_w, proj_b, cbias);
  k_genq<<<dim3(512), dim3(128), 0, stream>>>(Q_input, M, cbias, pq, qn2);
  k_genk<<<dim3(512), dim3(128), 0, stream>>>(K, proj_w, proj_b, pk, kn2);
  k_attn<<<dim3(512), dim3(256), 0, stream>>>(pq, qn2, pk, kn2, V, geo_w, temp, attn);
  k_wo<<<dim3(16, 64), dim3(256), 0, stream>>>(attn, Wo_w, Wo_b, out);
}

// Round 2
// 553.152 us; speedup vs baseline: 1.0286x; 1.0286x over previous
//
#include <hip/hip_runtime.h>
#include <hip/hip_bf16.h>
#include <math.h>

#define B_ 2
#define S_ 2048
#define D_ 1024
#define H_ 4
#define DK_ 256
#define NJ 24
#define NG 96
#define QT 32
#define KT 64

// ---------------- kernel 1: fold Wq into proj ----------------
// M[d][hj] = sum_k Wq_w[h*256+k][d] * proj_w[j][k]
__global__ __launch_bounds__(256) void k_fuse(const float* __restrict__ Wq_w,
                                              const float* __restrict__ proj_w,
                                              float* __restrict__ M) {
  int tid = blockIdx.x * 256 + threadIdx.x;  // 96*1024 threads
  int hj = tid >> 10;
  int d = tid & 1023;
  int h = hj / NJ, j = hj - h * NJ;
  const float* wq = Wq_w + (size_t)(h * DK_) * D_ + d;
  const float* pw = proj_w + j * DK_;
  float acc = 0.f;
#pragma unroll 8
  for (int k = 0; k < DK_; ++k) acc += wq[(size_t)k * D_] * pw[k];
  M[(size_t)d * NG + hj] = acc;
}

// cbias[hj] = sum_k Wq_b[h*256+k]*proj_w[j][k] + proj_b[j]
__global__ void k_fuse_bias(const float* __restrict__ Wq_b,
                            const float* __restrict__ proj_w,
                            const float* __restrict__ proj_b,
                            float* __restrict__ cbias) {
  int hj = threadIdx.x;
  if (hj < NG) {
    int h = hj / NJ, j = hj - h * NJ;
    float acc = proj_b[j];
    for (int k = 0; k < DK_; ++k) acc += Wq_b[h * DK_ + k] * proj_w[j * DK_ + k];
    cbias[hj] = acc;
  }
}

// ---------------- psi from gen rows (8 rows per block) ----------------
__device__ __forceinline__ void psi_store(const float (*genL)[NG], int t, int g0,
                                          float* __restrict__ po,
                                          float* __restrict__ n2o) {
  if (t < 64) {
    int h = t >> 4, ii = t & 15, j = ii & 7;
#pragma unroll 2
    for (int r = 0; r < 8; ++r) {
      int g = g0 + r;
      int b = g >> 11, s = g & (S_ - 1);
      const float* gl = genL[r] + h * NJ;
      float A = gl[j], Bg = gl[8 + j];
      float Th = fminf(fmaxf(gl[16 + j], -8.f), 8.f);
      float val = (ii < 8) ? (A * expf(Th) + Bg * cosf(Th)) : (Bg * sinf(Th));
      size_t base = (size_t)(b * H_ + h) * S_ + s;
      po[base * 16 + ii] = val;
      float sq = val * val;
#pragma unroll
      for (int off = 1; off < 16; off <<= 1) sq += __shfl_xor(sq, off);
      if (ii == 0) n2o[base] = sq;
    }
  }
}

// ---------------- gen_q = Q_input @ M + cbias, then psi ----------------
__global__ __launch_bounds__(128) void k_genq(const float* __restrict__ Q,
                                              const float* __restrict__ M,
                                              const float* __restrict__ cbias,
                                              float* __restrict__ pq,
                                              float* __restrict__ qn2) {
  __shared__ float qlds[8][D_];
  __shared__ float genL[8][NG];
  int t = threadIdx.x;
  int g0 = blockIdx.x * 8;
  {
    const float4* src = (const float4*)(Q + (size_t)g0 * D_);
    float4* dst = (float4*)&qlds[0][0];
#pragma unroll
    for (int u = 0; u < 16; ++u) dst[t + 128 * u] = src[t + 128 * u];
  }
  __syncthreads();
  if (t < NG) {
    float cb = cbias[t];
    float acc[8];
#pragma unroll
    for (int r = 0; r < 8; ++r) acc[r] = cb;
    const float* Mp = M + t;
#pragma unroll 2
    for (int d0 = 0; d0 < D_; d0 += 4) {
      float m0 = Mp[(size_t)(d0 + 0) * NG];
      float m1 = Mp[(size_t)(d0 + 1) * NG];
      float m2 = Mp[(size_t)(d0 + 2) * NG];
      float m3 = Mp[(size_t)(d0 + 3) * NG];
#pragma unroll
      for (int r = 0; r < 8; ++r) {
        float4 q4 = *(const float4*)&qlds[r][d0];
        acc[r] += q4.x * m0 + q4.y * m1 + q4.z * m2 + q4.w * m3;
      }
    }
#pragma unroll
    for (int r = 0; r < 8; ++r) genL[r][t] = acc[r];
  }
  __syncthreads();
  psi_store(genL, t, g0, pq, qn2);
}

// ---------------- gen_k = K_head @ proj_w.T + proj_b, then psi ----------------
__global__ __launch_bounds__(128) void k_genk(const float* __restrict__ Kin,
                                              const float* __restrict__ proj_w,
                                              const float* __restrict__ proj_b,
                                              float* __restrict__ pk,
                                              float* __restrict__ kn2) {
  __shared__ float klds[8][D_];
  __shared__ float genL[8][NG];
  __shared__ float pwT[DK_][NJ];
  int t = threadIdx.x;
  int g0 = blockIdx.x * 8;
  {
    const float4* src = (const float4*)(Kin + (size_t)g0 * D_);
    float4* dst = (float4*)&klds[0][0];
#pragma unroll
    for (int u = 0; u < 16; ++u) dst[t + 128 * u] = src[t + 128 * u];
  }
  for (int idx = t; idx < NJ * DK_; idx += 128) {
    int j = idx >> 8, c = idx & 255;
    pwT[c][j] = proj_w[idx];
  }
  __syncthreads();
  if (t < NG) {
    int h = t / NJ, j = t - h * NJ;
    float pb = proj_b[j];
    float acc[8];
#pragma unroll
    for (int r = 0; r < 8; ++r) acc[r] = pb;
#pragma unroll 2
    for (int c0 = 0; c0 < DK_; c0 += 4) {
      float w0 = pwT[c0][j], w1 = pwT[c0 + 1][j];
      float w2 = pwT[c0 + 2][j], w3 = pwT[c0 + 3][j];
#pragma unroll
      for (int r = 0; r < 8; ++r) {
        float4 k4 = *(const float4*)&klds[r][h * DK_ + c0];
        acc[r] += k4.x * w0 + k4.y * w1 + k4.z * w2 + k4.w * w3;
      }
    }
#pragma unroll
    for (int r = 0; r < 8; ++r) genL[r][t] = acc[r];
  }
  __syncthreads();
  psi_store(genL, t, g0, pk, kn2);
}

// ---------------- flash-style geometric attention (512 thr, KT=64) ----------------
// Thread roles:
//   scores: sr = t>>4 (row 0..31), kd = t&15 (4 k's: kd*4..kd*4+3)
//   PV:     rg = t&7 (rows rg*4..+3), cg = t>>3 (cols cg*4..+3)
// Wave-level LDS sharing: P-reads 8 unique b128, V-reads 8 unique b128 per kk.
__global__ __launch_bounds__(512, 4) void k_attn(
    const float* __restrict__ pq, const float* __restrict__ qn2,
    const float* __restrict__ pk, const float* __restrict__ kn2,
    const float* __restrict__ V, const float* __restrict__ geo_w,
    const float* __restrict__ temp, float* __restrict__ attn_out) {
  __shared__ float pkT[16][68];     // 4352 B
  __shared__ float Vs[KT][256];     // 65536 B
  __shared__ float Pt[KT][33];      // 8448 B
  __shared__ float kn2s[KT], khs[KT];
  __shared__ float mL[QT], lL[QT], fL[QT];

  int t = threadIdx.x;
  int bid = blockIdx.x;
  int bh = bid & 7;           // XCD-friendly: round-robin puts same bh on same XCD
  int qt = bid >> 3;
  int h = bh & (H_ - 1);
  int b = bh >> 2;
  int q0 = qt * QT;
  const float* pqb = pq + ((size_t)bh * S_ + q0) * 16;
  const float* pkb = pk + (size_t)bh * S_ * 16;
  const float* kn2b = kn2 + (size_t)bh * S_;
  const float* Vb = V + (size_t)b * S_ * D_ + h * DK_;

  float g0w = geo_w[0], g1w = geo_w[1], g2w = geo_w[2], g3w = geo_w[3];
  float scale = 1.f / (4.f * temp[0]);

  // score-role indices
  int sr = t >> 4, kd = t & 15;
  int kb = kd * 4;
  // PV-role indices
  int rg = t & 7, cg = t >> 3;

  // q row into registers (16 lanes redundantly read the same 64B - L1 broadcast)
  float qreg[16];
  {
    const float4* qp = (const float4*)(pqb + (size_t)sr * 16);
#pragma unroll
    for (int i = 0; i < 4; ++i) {
      float4 v = qp[i];
      qreg[i * 4 + 0] = v.x; qreg[i * 4 + 1] = v.y;
      qreg[i * 4 + 2] = v.z; qreg[i * 4 + 3] = v.w;
    }
  }
  float myqn2 = 0.f;
#pragma unroll
  for (int i = 0; i < 16; ++i) myqn2 += qreg[i] * qreg[i];
  float myqh = sqrtf(myqn2 + 1e-6f);

  if (t < QT) { mL[t] = -INFINITY; lL[t] = 0.f; }

  float acc[4][4];
#pragma unroll
  for (int i = 0; i < 4; ++i)
#pragma unroll
    for (int j = 0; j < 4; ++j) acc[i][j] = 0.f;

  int vc = t & 63;         // f4 col for V staging
  int vw = t >> 6;         // wave id 0..7 -> rows vw*8..vw*8+7

  for (int kt = 0; kt < S_ / KT; ++kt) {
    int k0 = kt * KT;
    // ---- stage V tile (64x256 f32) ----
    {
      const float* vsrc = Vb + (size_t)(k0 + vw * 8) * D_ + vc * 4;
#pragma unroll
      for (int u = 0; u < 8; ++u) {
        float4 v4 = *(const float4*)(vsrc + (size_t)u * D_);
        *(float4*)&Vs[vw * 8 + u][vc * 4] = v4;
      }
    }
    // ---- stage pk transposed + kn2 ----
    if (t < 256) {
      int kr = t >> 2, i0 = (t & 3) * 4;
      float4 v = *(const float4*)(pkb + (size_t)(k0 + kr) * 16 + i0);
      pkT[i0 + 0][kr] = v.x; pkT[i0 + 1][kr] = v.y;
      pkT[i0 + 2][kr] = v.z; pkT[i0 + 3][kr] = v.w;
    } else if (t < 256 + KT) {
      int k = t - 256;
      float kv = kn2b[k0 + k];
      kn2s[k] = kv;
      khs[k] = sqrtf(kv + 1e-6f);
    }
    __syncthreads();

    // ---- scores: thread (sr, kd) computes k = kb..kb+3 ----
    float tns[4] = {0.f, 0.f, 0.f, 0.f}, spn[4] = {0.f, 0.f, 0.f, 0.f};
#pragma unroll
    for (int i = 0; i < 8; ++i) {
      float4 ka = *(const float4*)&pkT[i][kb];
      float4 kc = *(const float4*)&pkT[i + 8][kb];
      float qa = qreg[i], qb = qreg[i + 8];
      tns[0] += qa * ka.x + qb * kc.x;
      tns[1] += qa * ka.y + qb * kc.y;
      tns[2] += qa * ka.z + qb * kc.z;
      tns[3] += qa * ka.w + qb * kc.w;
      spn[0] += qa * kc.x - qb * ka.x;
      spn[1] += qa * kc.y - qb * ka.y;
      spn[2] += qa * kc.z - qb * ka.z;
      spn[3] += qa * kc.w - qb * ka.w;
    }
    float sc4[4];
    float tmax = -INFINITY;
#pragma unroll
    for (int kk = 0; kk < 4; ++kk) {
      float tn = tns[kk], sp = spn[kk];
      float gram = myqn2 * kn2s[kb + kk];
      float wedge = sqrtf(fmaxf(gram - tn * tn - sp * sp, 0.f) + 1e-6f);
      float sv = (g0w * wedge + g1w * tn + g2w * sp + g3w * (myqh * khs[kb + kk])) * scale;
      sc4[kk] = sv;
      tmax = fmaxf(tmax, sv);
    }
#pragma unroll
    for (int off = 1; off < 16; off <<= 1) tmax = fmaxf(tmax, __shfl_xor(tmax, off));
    float mo = mL[sr];
    float mn = fmaxf(mo, tmax);
    float psum = 0.f;
#pragma unroll
    for (int kk = 0; kk < 4; ++kk) {
      float p = __expf(sc4[kk] - mn);
      Pt[kb + kk][sr] = p;
      psum += p;
    }
#pragma unroll
    for (int off = 1; off < 16; off <<= 1) psum += __shfl_xor(psum, off);
    if (kd == 0) {
      float fsc = __expf(mo - mn);
      mL[sr] = mn;
      lL[sr] = lL[sr] * fsc + psum;
      fL[sr] = fsc;
    }
    __syncthreads();

    // ---- PV: rows rg*4+rr, cols cg*4+cc ----
    {
      float fr[4];
#pragma unroll
      for (int rr = 0; rr < 4; ++rr) fr[rr] = fL[rg * 4 + rr];
#pragma unroll
      for (int rr = 0; rr < 4; ++rr)
#pragma unroll
        for (int cc = 0; cc < 4; ++cc) acc[rr][cc] *= fr[rr];
#pragma unroll 8
      for (int kk = 0; kk < KT; ++kk) {
        float4 p4 = *(const float4*)&Pt[kk][rg * 4];
        float4 v4 = *(const float4*)&Vs[kk][cg * 4];
        float pr[4] = {p4.x, p4.y, p4.z, p4.w};
#pragma unroll
        for (int rr = 0; rr < 4; ++rr) {
          acc[rr][0] += pr[rr] * v4.x;
          acc[rr][1] += pr[rr] * v4.y;
          acc[rr][2] += pr[rr] * v4.z;
          acc[rr][3] += pr[rr] * v4.w;
        }
      }
    }
    __syncthreads();
  }

#pragma unroll
  for (int rr = 0; rr < 4; ++rr) {
    int r = rg * 4 + rr;
    float linv = 1.f / lL[r];
    float* dst = attn_out + ((size_t)b * S_ + q0 + r) * D_ + h * DK_ + cg * 4;
    float4 o = make_float4(acc[rr][0] * linv, acc[rr][1] * linv,
                           acc[rr][2] * linv, acc[rr][3] * linv);
    *(float4*)dst = o;
  }
}

// ---------------- output projection: C = A @ W^T + bias ----------------
__global__ __launch_bounds__(256) void k_wo(const float* __restrict__ A,
                                            const float* __restrict__ W,
                                            const float* __restrict__ bias,
                                            float* __restrict__ C) {
  __shared__ float As[32][68];
  __shared__ float Bs[32][68];
  int t = threadIdx.x;
  int tx = t & 15, ty = t >> 4;
  int n0 = blockIdx.x * 64;
  int m0 = blockIdx.y * 64;
  float acc[4][4];
#pragma unroll
  for (int i = 0; i < 4; ++i)
#pragma unroll
    for (int j = 0; j < 4; ++j) acc[i][j] = 0.f;

  for (int k0 = 0; k0 < D_; k0 += 32) {
#pragma unroll
    for (int u = 0; u < 2; ++u) {
      int idx = t + 256 * u;
      int row = idx >> 3, cf = idx & 7;
      float4 a = *(const float4*)(A + (size_t)(m0 + row) * D_ + k0 + cf * 4);
      As[cf * 4 + 0][row] = a.x; As[cf * 4 + 1][row] = a.y;
      As[cf * 4 + 2][row] = a.z; As[cf * 4 + 3][row] = a.w;
      float4 bb = *(const float4*)(W + (size_t)(n0 + row) * D_ + k0 + cf * 4);
      Bs[cf * 4 + 0][row] = bb.x; Bs[cf * 4 + 1][row] = bb.y;
      Bs[cf * 4 + 2][row] = bb.z; Bs[cf * 4 + 3][row] = bb.w;
    }
    __syncthreads();
#pragma unroll 8
    for (int kk = 0; kk < 32; ++kk) {
      float4 a4 = *(const float4*)&As[kk][ty * 4];
      float4 b4 = *(const float4*)&Bs[kk][tx * 4];
      float av[4] = {a4.x, a4.y, a4.z, a4.w};
      float bv[4] = {b4.x, b4.y, b4.z, b4.w};
#pragma unroll
      for (int i = 0; i < 4; ++i)
#pragma unroll
        for (int j = 0; j < 4; ++j) acc[i][j] += av[i] * bv[j];
    }
    __syncthreads();
  }
  float4 b4 = *(const float4*)(bias + n0 + tx * 4);
  float bv[4] = {b4.x, b4.y, b4.z, b4.w};
#pragma unroll
  for (int i = 0; i < 4; ++i) {
    float4 o = make_float4(acc[i][0] + bv[0], acc[i][1] + bv[1],
                           acc[i][2] + bv[2], acc[i][3] + bv[3]);
    *(float4*)(C + (size_t)(m0 + ty * 4 + i) * D_ + n0 + tx * 4) = o;
  }
}

extern "C" void kernel_launch(void* const* d_in, const int* in_sizes, int n_in,
                              void* d_out, int out_size, void* d_ws, size_t ws_size,
                              hipStream_t stream) {
  const float* Q_input = (const float*)d_in[0];
  const float* K = (const float*)d_in[1];
  const float* V = (const float*)d_in[2];
  // d_in[3] = T_field: unused by the reference
  const float* Wq_w = (const float*)d_in[4];
  const float* Wq_b = (const float*)d_in[5];
  const float* Wo_w = (const float*)d_in[6];
  const float* Wo_b = (const float*)d_in[7];
  const float* proj_w = (const float*)d_in[8];
  const float* proj_b = (const float*)d_in[9];
  const float* geo_w = (const float*)d_in[10];
  const float* temp = (const float*)d_in[11];

  float* ws = (float*)d_ws;
  float* M = ws;                       // 1024*96      = 98304
  float* cbias = M + 98304;            // 96 (pad 128)
  float* pq = cbias + 128;             // 2*4*2048*16  = 262144
  float* qn2 = pq + 262144;            // 16384
  float* pk = qn2 + 16384;             // 262144
  float* kn2 = pk + 262144;            // 16384
  float* attn = kn2 + 16384;           // 2*2048*1024  = 4194304
  float* out = (float*)d_out;

  k_fuse<<<dim3(384), dim3(256), 0, stream>>>(Wq_w, proj_w, M);
  k_fuse_bias<<<dim3(1), dim3(128), 0, stream>>>(Wq_b, proj_w, proj_b, cbias);
  k_genq<<<dim3(512), dim3(128), 0, stream>>>(Q_input, M, cbias, pq, qn2);
  k_genk<<<dim3(512), dim3(128), 0, stream>>>(K, proj_w, proj_b, pk, kn2);
  k_attn<<<dim3(512), dim3(512), 0, stream>>>(pq, qn2, pk, kn2, V, geo_w, temp, attn);
  k_wo<<<dim3(16, 64), dim3(256), 0, stream>>>(attn, Wo_w, Wo_b, out);
}